// Round 2
// baseline (127.353 us; speedup 1.0000x reference)
//
#include <hip/hip_runtime.h>
#include <math.h>

// FraudDetectionNet, restructured:
//  - patch_kernel: one thread per (image, patch) -- all 64 lanes of every wave
//    active (was 196/256). Computes per-patch pixel sum/sumsq and the folded
//    quantum contribution qsum = sum_k |U_k . psi|^2 * zc_k, then does a
//    segmented wave reduction (a 64-lane span covers at most 2 images since
//    196 >= 64) and atomicAdd's into per-image partials in d_ws.
//  - final_kernel: one thread per image -- mean/std -> tanh MLP -> fuse with
//    quantum sum -> sigmoid.
// d_ws layout: [S(8192) | SS(8192) | QS(8192)] floats, zeroed via memsetAsync.

#define NPATCH 196
#define NIMG   8192
#define NTOTAL (NIMG * NPATCH)   // 1,605,632 = 6272 * 256

__global__ __launch_bounds__(256) void patch_kernel(
    const float* __restrict__ x,        // (8192, 784)
    const float* __restrict__ U_re,     // (16,16)
    const float* __restrict__ U_im,     // (16,16)
    const float* __restrict__ w_cls,    // (785,)
    float* __restrict__ accS,
    float* __restrict__ accSS,
    float* __restrict__ accQ)
{
    const int g    = blockIdx.x * 256 + threadIdx.x;   // exact grid, no bounds check
    const int img  = g / NPATCH;
    const int p    = g - img * NPATCH;
    const int r    = p / 14;
    const int c    = p - r * 14;
    const int lane = threadIdx.x & 63;

    const float* xp = x + (size_t)img * 784;
    // patch pixels: [x[2r,2c], x[2r,2c+1], x[2r+1,2c], x[2r+1,2c+1]]
    const float2 top = *(const float2*)(xp + (2 * r) * 28 + 2 * c);
    const float2 bot = *(const float2*)(xp + (2 * r + 1) * 28 + 2 * c);
    const float x0 = top.x, x1 = top.y, x2 = bot.x, x3 = bot.y;

    float sum   = x0 + x1 + x2 + x3;
    float sumsq = x0 * x0 + x1 * x1 + x2 * x2 + x3 * x3;

    // RY(theta)|0> amplitudes
    const float c0 = __cosf(0.5f * x0), s0 = __sinf(0.5f * x0);
    const float c1 = __cosf(0.5f * x1), s1 = __sinf(0.5f * x1);
    const float c2 = __cosf(0.5f * x2), s2 = __sinf(0.5f * x2);
    const float c3 = __cosf(0.5f * x3), s3 = __sinf(0.5f * x3);

    float p01[4] = { c0 * c1, c0 * s1, s0 * c1, s0 * s1 };
    float p23[4] = { c2 * c3, c2 * s3, s2 * c3, s2 * s3 };
    float psi[16];
    #pragma unroll
    for (int h = 0; h < 4; ++h)
        #pragma unroll
        for (int l = 0; l < 4; ++l)
            psi[h * 4 + l] = p01[h] * p23[l];

    // fold PauliZ + classifier weights: zc[k] = hi[k>>2] + lo[k&3]
    const float wq0 = w_cls[1 + p * 4 + 0];
    const float wq1 = w_cls[1 + p * 4 + 1];
    const float wq2 = w_cls[1 + p * 4 + 2];
    const float wq3 = w_cls[1 + p * 4 + 3];
    float hi[4] = { wq0 + wq1, wq0 - wq1, -wq0 + wq1, -wq0 - wq1 };
    float lo[4] = { wq2 + wq3, wq2 - wq3, -wq2 + wq3, -wq2 - wq3 };

    float qsum = 0.f;
    #pragma unroll
    for (int k = 0; k < 16; ++k) {
        const float* ur = U_re + k * 16;   // wave-uniform -> scalar loads
        const float* ui = U_im + k * 16;
        float re = 0.f, im = 0.f;
        #pragma unroll
        for (int m = 0; m < 16; ++m) {
            re = fmaf(ur[m], psi[m], re);
            im = fmaf(ui[m], psi[m], im);
        }
        const float prob = re * re + im * im;
        qsum = fmaf(prob, hi[k >> 2] + lo[k & 3], qsum);
    }

    // ---- segmented wave reduction (<=2 images per 64-lane span) ----
    const int imgF = __builtin_amdgcn_readfirstlane(img);
    const bool first = (img == imgF);
    float aS = first ? sum   : 0.f;  float bS = sum   - aS;
    float aV = first ? sumsq : 0.f;  float bV = sumsq - aV;
    float aQ = first ? qsum  : 0.f;  float bQ = qsum  - aQ;

    #pragma unroll
    for (int off = 1; off < 64; off <<= 1) {
        aS += __shfl_xor(aS, off, 64);  bS += __shfl_xor(bS, off, 64);
        aV += __shfl_xor(aV, off, 64);  bV += __shfl_xor(bV, off, 64);
        aQ += __shfl_xor(aQ, off, 64);  bQ += __shfl_xor(bQ, off, 64);
    }

    if (lane == 0) {
        atomicAdd(accS  + imgF, aS);
        atomicAdd(accSS + imgF, aV);
        atomicAdd(accQ  + imgF, aQ);
    }
    if (lane == 63 && img != imgF) {   // second image's segment
        atomicAdd(accS  + img, bS);
        atomicAdd(accSS + img, bV);
        atomicAdd(accQ  + img, bQ);
    }
}

__global__ __launch_bounds__(256) void final_kernel(
    const float* __restrict__ accS,
    const float* __restrict__ accSS,
    const float* __restrict__ accQ,
    const float* __restrict__ w_in,     // (2,2)
    const float* __restrict__ b_in,     // (2,)
    const float* __restrict__ scale_in, // (2,)
    const float* __restrict__ shift_in, // (2,)
    const float* __restrict__ Wc,       // (2,2,2)
    const float* __restrict__ bc,       // (2,2)
    const float* __restrict__ scalec,   // (2,2)
    const float* __restrict__ shiftc,   // (2,2)
    const float* __restrict__ w_out,    // (1,2)
    const float* __restrict__ b_out,    // (1,)
    const float* __restrict__ w_cls,    // (785,)
    const float* __restrict__ b_cls,    // (1,)
    float* __restrict__ out)            // (8192,)
{
    const int i = blockIdx.x * 256 + threadIdx.x;
    const float S  = accS[i];
    const float SS = accSS[i];
    const float QS = accQ[i];

    const float mean = S * (1.f / 784.f);
    float var = (SS - S * S * (1.f / 784.f)) * (1.f / 783.f);  // ddof=1
    var = fmaxf(var, 0.f);
    const float stdv = sqrtf(var);

    float h0 = mean, h1 = stdv;
    {
        const float t0 = tanhf(h0 * w_in[0] + h1 * w_in[1] + b_in[0]);
        const float t1 = tanhf(h0 * w_in[2] + h1 * w_in[3] + b_in[1]);
        h0 = t0 * scale_in[0] + shift_in[0];
        h1 = t1 * scale_in[1] + shift_in[1];
    }
    #pragma unroll
    for (int l = 0; l < 2; ++l) {
        const float t0 = tanhf(h0 * Wc[l * 4 + 0] + h1 * Wc[l * 4 + 1] + bc[l * 2 + 0]);
        const float t1 = tanhf(h0 * Wc[l * 4 + 2] + h1 * Wc[l * 4 + 3] + bc[l * 2 + 1]);
        h0 = t0 * scalec[l * 2 + 0] + shiftc[l * 2 + 0];
        h1 = t1 * scalec[l * 2 + 1] + shiftc[l * 2 + 1];
    }
    const float cls   = h0 * w_out[0] + h1 * w_out[1] + b_out[0];
    const float logit = b_cls[0] + w_cls[0] * cls + QS;
    out[i] = 1.f / (1.f + __expf(-logit));
}

extern "C" void kernel_launch(void* const* d_in, const int* in_sizes, int n_in,
                              void* d_out, int out_size, void* d_ws, size_t ws_size,
                              hipStream_t stream) {
    const float* x        = (const float*)d_in[0];
    const float* w_in     = (const float*)d_in[1];
    const float* b_in     = (const float*)d_in[2];
    const float* scale_in = (const float*)d_in[3];
    const float* shift_in = (const float*)d_in[4];
    const float* Wc       = (const float*)d_in[5];
    const float* bc       = (const float*)d_in[6];
    const float* scalec   = (const float*)d_in[7];
    const float* shiftc   = (const float*)d_in[8];
    const float* w_out    = (const float*)d_in[9];
    const float* b_out    = (const float*)d_in[10];
    const float* U_re     = (const float*)d_in[11];
    const float* U_im     = (const float*)d_in[12];
    const float* w_cls    = (const float*)d_in[13];
    const float* b_cls    = (const float*)d_in[14];
    float* out = (float*)d_out;

    float* accS  = (float*)d_ws;
    float* accSS = accS + NIMG;
    float* accQ  = accSS + NIMG;

    // zero the partials (ws is poisoned 0xAA before every launch)
    hipMemsetAsync(d_ws, 0, 3 * NIMG * sizeof(float), stream);

    patch_kernel<<<NTOTAL / 256, 256, 0, stream>>>(x, U_re, U_im, w_cls,
                                                   accS, accSS, accQ);
    final_kernel<<<NIMG / 256, 256, 0, stream>>>(accS, accSS, accQ,
                                                 w_in, b_in, scale_in, shift_in,
                                                 Wc, bc, scalec, shiftc,
                                                 w_out, b_out, w_cls, b_cls, out);
}